// Round 1
// baseline (3128.846 us; speedup 1.0000x reference)
//
#include <hip/hip_runtime.h>

constexpr int Bc = 4;     // batch
constexpr int Cc = 256;   // channels
constexpr int Dc = 64;    // q/k dim
constexpr int Nc = 4096;  // sequence length

// ---------------------------------------------------------------------------
// conv1x1: Y[b,o,n] = sum_c W[o,c] * X[b,c,n]
// grid: (Nc/64, O/64, B), block 256. 64x64 tile, K-step 16.
// ---------------------------------------------------------------------------
__global__ __launch_bounds__(256) void conv1x1_kernel(
    const float* __restrict__ W, const float* __restrict__ X,
    float* __restrict__ Y, int O)
{
  __shared__ float Ws[16][68];  // [k][o], padded
  __shared__ float Xs[16][68];  // [k][n], padded
  const int t  = threadIdx.x;
  const int n0 = blockIdx.x * 64;
  const int o0 = blockIdx.y * 64;
  const int b  = blockIdx.z;
  const float* Xb = X + (size_t)b * Cc * Nc;
  const int tx = t & 15, ty = t >> 4;

  const int wo = t >> 2, wk = (t & 3) * 4;   // W-tile loader coords
  const int xk = t >> 4, xn = (t & 15) * 4;  // X-tile loader coords

  float acc[4][4] = {};

  for (int k0 = 0; k0 < Cc; k0 += 16) {
    float4 w4 = *(const float4*)&W[(size_t)(o0 + wo) * Cc + k0 + wk];
    float4 x4 = *(const float4*)&Xb[(size_t)(k0 + xk) * Nc + n0 + xn];
    Ws[wk + 0][wo] = w4.x;
    Ws[wk + 1][wo] = w4.y;
    Ws[wk + 2][wo] = w4.z;
    Ws[wk + 3][wo] = w4.w;
    *(float4*)&Xs[xk][xn] = x4;
    __syncthreads();
#pragma unroll
    for (int kk = 0; kk < 16; ++kk) {
      float4 av = *(const float4*)&Ws[kk][ty * 4];
      float4 bv = *(const float4*)&Xs[kk][tx * 4];
      float aa[4] = {av.x, av.y, av.z, av.w};
      float bb[4] = {bv.x, bv.y, bv.z, bv.w};
#pragma unroll
      for (int i = 0; i < 4; ++i)
#pragma unroll
        for (int j = 0; j < 4; ++j)
          acc[i][j] += aa[i] * bb[j];
    }
    __syncthreads();
  }

#pragma unroll
  for (int i = 0; i < 4; ++i) {
    float4 o4 = make_float4(acc[i][0], acc[i][1], acc[i][2], acc[i][3]);
    *(float4*)&Y[((size_t)b * O + o0 + ty * 4 + i) * Nc + n0 + tx * 4] = o4;
  }
}

// ---------------------------------------------------------------------------
// Flash-style attention (fp32):
//   R[b,c,m] = sum_n V[b,c,n] * softmax_n(sum_d Q[b,d,m] K[b,d,n])
// grid: (Nc/32, B), block 256 (4 waves). 32 queries/block, 32-n tiles.
// Thread t: query row qi = t>>3, channel group g = t&7,
//   owns channels c = g*4 + j4*32 + i  (j4=0..7, i=0..3) -> 32 accumulators.
// ---------------------------------------------------------------------------
__global__ __launch_bounds__(256) void attn_kernel(
    const float* __restrict__ Q, const float* __restrict__ K,
    const float* __restrict__ V, float* __restrict__ R)
{
  __shared__ float q_lds[64][36];   // [d][mi], pad 36 -> conflict-free
  __shared__ float k_lds[64][36];   // [d][ni]
  __shared__ float v_lds[32][260];  // [ni][c], pad 260
  __shared__ float p_lds[32][33];   // [qi][ni]
  __shared__ float m_run[32], l_run[32], s_fac[32];

  const int t  = threadIdx.x;
  const int b  = blockIdx.y;
  const int m0 = blockIdx.x * 32;
  const float* Qb = Q + (size_t)b * Dc * Nc;
  const float* Kb = K + (size_t)b * Dc * Nc;
  const float* Vb = V + (size_t)b * Cc * Nc;

  const int qi = t >> 3;
  const int g  = t & 7;

#pragma unroll
  for (int rep = 0; rep < 8; ++rep) {       // q tile: 64d x 32m
    int idx = rep * 256 + t;
    int d = idx >> 5, mi = idx & 31;
    q_lds[d][mi] = Qb[(size_t)d * Nc + m0 + mi];
  }
  if (t < 32) { m_run[t] = -3.0e38f; l_run[t] = 0.f; }
  float acc[8][4] = {};
  __syncthreads();

  for (int n0 = 0; n0 < Nc; n0 += 32) {
#pragma unroll
    for (int rep = 0; rep < 8; ++rep) {     // k tile: 64d x 32n
      int idx = rep * 256 + t;
      int d = idx >> 5, ni = idx & 31;
      k_lds[d][ni] = Kb[(size_t)d * Nc + n0 + ni];
    }
#pragma unroll
    for (int rep = 0; rep < 32; ++rep) {    // v tile: 256c x 32n (stored [ni][c])
      int idx = rep * 256 + t;
      int c = idx >> 5, ni = idx & 31;
      v_lds[ni][c] = Vb[(size_t)c * Nc + n0 + ni];
    }
    __syncthreads();

    // energies: 4 per thread, e[qi][g*4 + jj]
    float e0 = 0.f, e1 = 0.f, e2 = 0.f, e3 = 0.f;
#pragma unroll
    for (int k = 0; k < 64; ++k) {
      float qv = q_lds[k][qi];
      float4 kv = *(const float4*)&k_lds[k][g * 4];
      e0 += qv * kv.x; e1 += qv * kv.y; e2 += qv * kv.z; e3 += qv * kv.w;
    }

    // row max / sum across the 8 lanes sharing qi (same wave, lanes differ in bits 0..2)
    float mymax = fmaxf(fmaxf(e0, e1), fmaxf(e2, e3));
#pragma unroll
    for (int off = 1; off < 8; off <<= 1)
      mymax = fmaxf(mymax, __shfl_xor(mymax, off));
    float mprev = m_run[qi];
    float mnew  = fmaxf(mprev, mymax);
    float p0 = __expf(e0 - mnew), p1 = __expf(e1 - mnew);
    float p2 = __expf(e2 - mnew), p3 = __expf(e3 - mnew);
    float mysum = p0 + p1 + p2 + p3;
#pragma unroll
    for (int off = 1; off < 8; off <<= 1)
      mysum += __shfl_xor(mysum, off);

    p_lds[qi][g * 4 + 0] = p0;
    p_lds[qi][g * 4 + 1] = p1;
    p_lds[qi][g * 4 + 2] = p2;
    p_lds[qi][g * 4 + 3] = p3;
    if (g == 0) {
      float sc = __expf(mprev - mnew);
      s_fac[qi] = sc;
      m_run[qi] = mnew;
      l_run[qi] = l_run[qi] * sc + mysum;
    }
    __syncthreads();  // publish p_lds/s_fac (also keeps waves in phase)

    float sc = s_fac[qi];
#pragma unroll
    for (int j4 = 0; j4 < 8; ++j4)
#pragma unroll
      for (int i = 0; i < 4; ++i) acc[j4][i] *= sc;

    for (int ni = 0; ni < 32; ++ni) {
      float w = p_lds[qi][ni];
#pragma unroll
      for (int j4 = 0; j4 < 8; ++j4) {
        float4 v4 = *(const float4*)&v_lds[ni][g * 4 + j4 * 32];
        acc[j4][0] += w * v4.x; acc[j4][1] += w * v4.y;
        acc[j4][2] += w * v4.z; acc[j4][3] += w * v4.w;
      }
    }
    __syncthreads();  // done with k/v tiles before next load
  }

  const float linv = 1.0f / l_run[qi];
  // transpose-dump through LDS (reuse v_lds: 256*32 = 8192 <= 32*260)
  float* dump = &v_lds[0][0];
#pragma unroll
  for (int j4 = 0; j4 < 8; ++j4)
#pragma unroll
    for (int i = 0; i < 4; ++i)
      dump[(size_t)(g * 4 + j4 * 32 + i) * 32 + qi] = acc[j4][i] * linv;
  __syncthreads();
#pragma unroll
  for (int rep = 0; rep < 32; ++rep) {
    int idx = rep * 256 + t;
    int c = idx >> 5, mi = idx & 31;
    R[((size_t)b * Cc + c) * Nc + m0 + mi] = dump[idx];
  }
}

// ---------------------------------------------------------------------------
// BN stats: per channel mean and rsqrt(var+eps) over (B, N). grid: C blocks.
// ---------------------------------------------------------------------------
__global__ __launch_bounds__(256) void bn_stats_kernel(
    const float* __restrict__ T, float* __restrict__ stats)
{
  const int c = blockIdx.x, t = threadIdx.x;
  float s = 0.f, ss = 0.f;
  for (int i = t; i < Bc * Nc; i += 256) {
    int b = i >> 12, n = i & (Nc - 1);
    float v = T[((size_t)b * Cc + c) * Nc + n];
    s += v; ss += v * v;
  }
#pragma unroll
  for (int off = 1; off < 64; off <<= 1) {
    s  += __shfl_xor(s, off);
    ss += __shfl_xor(ss, off);
  }
  __shared__ float rs[4], rss[4];
  int w = t >> 6;
  if ((t & 63) == 0) { rs[w] = s; rss[w] = ss; }
  __syncthreads();
  if (t == 0) {
    s  = rs[0] + rs[1] + rs[2] + rs[3];
    ss = rss[0] + rss[1] + rss[2] + rss[3];
    float inv_n = 1.0f / (float)(Bc * Nc);
    float mean = s * inv_n;
    float var  = ss * inv_n - mean * mean;
    stats[c]      = mean;
    stats[Cc + c] = rsqrtf(var + 1e-5f);
  }
}

// ---------------------------------------------------------------------------
// Epilogue: OUT = SRC + relu(gamma*(T-mean)*istd + beta). float4 over 4M elems.
// ---------------------------------------------------------------------------
__global__ __launch_bounds__(256) void bn_out_kernel(
    const float* __restrict__ T, const float* __restrict__ SRC,
    const float* __restrict__ stats, const float* __restrict__ gamma,
    const float* __restrict__ beta, float* __restrict__ OUT)
{
  const int i = blockIdx.x * 256 + threadIdx.x;
  const int flat = i << 2;
  const int c = (flat >> 12) & (Cc - 1);
  float mean = stats[c], istd = stats[Cc + c];
  float gm = gamma[c], bt = beta[c];
  float4 t4 = *(const float4*)&T[flat];
  float4 s4 = *(const float4*)&SRC[flat];
  float4 o4;
  o4.x = s4.x + fmaxf(0.f, gm * (t4.x - mean) * istd + bt);
  o4.y = s4.y + fmaxf(0.f, gm * (t4.y - mean) * istd + bt);
  o4.z = s4.z + fmaxf(0.f, gm * (t4.z - mean) * istd + bt);
  o4.w = s4.w + fmaxf(0.f, gm * (t4.w - mean) * istd + bt);
  *(float4*)&OUT[flat] = o4;
}

// ---------------------------------------------------------------------------
extern "C" void kernel_launch(void* const* d_in, const int* in_sizes, int n_in,
                              void* d_out, int out_size, void* d_ws, size_t ws_size,
                              hipStream_t stream) {
  const float* x     = (const float*)d_in[0];
  const float* y     = (const float*)d_in[1];
  const float* w_qkx = (const float*)d_in[2];
  const float* w_vx  = (const float*)d_in[3];
  const float* w_tx  = (const float*)d_in[4];
  const float* w_qky = (const float*)d_in[5];
  const float* w_vy  = (const float*)d_in[6];
  const float* w_ty  = (const float*)d_in[7];
  const float* gamma = (const float*)d_in[8];
  const float* beta  = (const float*)d_in[9];

  float* out0 = (float*)d_out;
  float* out1 = out0 + (size_t)Bc * Cc * Nc;

  float* ws = (float*)d_ws;
  float* qb = ws;                              // B*D*N
  float* kb = qb + (size_t)Bc * Dc * Nc;       // B*D*N
  float* vb = kb + (size_t)Bc * Dc * Nc;       // B*C*N
  float* rb = vb + (size_t)Bc * Cc * Nc;       // B*C*N
  float* tb = rb + (size_t)Bc * Cc * Nc;       // B*C*N
  float* st = tb + (size_t)Bc * Cc * Nc;       // 2*C

  for (int br = 0; br < 2; ++br) {
    const float* src = (br == 0) ? x : y;
    const float* tgt = (br == 0) ? y : x;
    const float* wqk = (br == 0) ? w_qkx : w_qky;
    const float* wv  = (br == 0) ? w_vx  : w_vy;
    const float* wt  = (br == 0) ? w_tx  : w_ty;
    float* out       = (br == 0) ? out0 : out1;

    // q = wqk @ tgt, k = wqk @ src, v = wv @ src
    conv1x1_kernel<<<dim3(Nc / 64, Dc / 64, Bc), 256, 0, stream>>>(wqk, tgt, qb, Dc);
    conv1x1_kernel<<<dim3(Nc / 64, Dc / 64, Bc), 256, 0, stream>>>(wqk, src, kb, Dc);
    conv1x1_kernel<<<dim3(Nc / 64, Cc / 64, Bc), 256, 0, stream>>>(wv, src, vb, Cc);
    // r = attention(q, k, v)
    attn_kernel<<<dim3(Nc / 32, Bc), 256, 0, stream>>>(qb, kb, vb, rb);
    // t = wt @ r
    conv1x1_kernel<<<dim3(Nc / 64, Cc / 64, Bc), 256, 0, stream>>>(wt, rb, tb, Cc);
    // BN stats + epilogue
    bn_stats_kernel<<<Cc, 256, 0, stream>>>(tb, st);
    bn_out_kernel<<<(Bc * Cc * Nc / 4) / 256, 256, 0, stream>>>(tb, src, st, gamma, beta, out);
  }
}

// Round 2
// 514.776 us; speedup vs baseline: 6.0781x; 6.0781x over previous
//
#include <hip/hip_runtime.h>

constexpr int Bc = 4;     // batch
constexpr int Cc = 256;   // channels
constexpr int Dc = 64;    // q/k dim
constexpr int Nc = 4096;  // sequence length

typedef __attribute__((ext_vector_type(8))) short bf16x8;
typedef __attribute__((ext_vector_type(4))) short bf16x4;
typedef __attribute__((ext_vector_type(4))) float f32x4;

__device__ inline short f2bf(float x) {
  union { float f; unsigned u; } v; v.f = x;
  unsigned r = v.u + 0x7fffu + ((v.u >> 16) & 1u);
  return (short)(r >> 16);
}
__device__ inline float bf2f(short h) {
  union { unsigned u; float f; } v; v.u = ((unsigned)(unsigned short)h) << 16;
  return v.f;
}

// ---------------------------------------------------------------------------
// conv1x1 fp32 (used for t = w_t @ r): Y[b,o,n] = sum_c W[o,c] * X[b,c,n]
// ---------------------------------------------------------------------------
__global__ __launch_bounds__(256) void conv1x1_kernel(
    const float* __restrict__ W, const float* __restrict__ X,
    float* __restrict__ Y, int O)
{
  __shared__ float Ws[16][68];
  __shared__ float Xs[16][68];
  const int t  = threadIdx.x;
  const int n0 = blockIdx.x * 64;
  const int o0 = blockIdx.y * 64;
  const int b  = blockIdx.z;
  const float* Xb = X + (size_t)b * Cc * Nc;
  const int tx = t & 15, ty = t >> 4;
  const int wo = t >> 2, wk = (t & 3) * 4;
  const int xk = t >> 4, xn = (t & 15) * 4;
  float acc[4][4] = {};
  for (int k0 = 0; k0 < Cc; k0 += 16) {
    float4 w4 = *(const float4*)&W[(size_t)(o0 + wo) * Cc + k0 + wk];
    float4 x4 = *(const float4*)&Xb[(size_t)(k0 + xk) * Nc + n0 + xn];
    Ws[wk + 0][wo] = w4.x; Ws[wk + 1][wo] = w4.y;
    Ws[wk + 2][wo] = w4.z; Ws[wk + 3][wo] = w4.w;
    *(float4*)&Xs[xk][xn] = x4;
    __syncthreads();
#pragma unroll
    for (int kk = 0; kk < 16; ++kk) {
      float4 av = *(const float4*)&Ws[kk][ty * 4];
      float4 bv = *(const float4*)&Xs[kk][tx * 4];
      float aa[4] = {av.x, av.y, av.z, av.w};
      float bb[4] = {bv.x, bv.y, bv.z, bv.w};
#pragma unroll
      for (int i = 0; i < 4; ++i)
#pragma unroll
        for (int j = 0; j < 4; ++j) acc[i][j] += aa[i] * bb[j];
    }
    __syncthreads();
  }
#pragma unroll
  for (int i = 0; i < 4; ++i) {
    float4 o4 = make_float4(acc[i][0], acc[i][1], acc[i][2], acc[i][3]);
    *(float4*)&Y[((size_t)b * O + o0 + ty * 4 + i) * Nc + n0 + tx * 4] = o4;
  }
}

// ---------------------------------------------------------------------------
// conv1x1 -> bf16 TRANSPOSED output [b][n][64] (for q_t / k_t). O = 64.
// ---------------------------------------------------------------------------
__global__ __launch_bounds__(256) void conv_qk_bf16t_kernel(
    const float* __restrict__ W, const float* __restrict__ X,
    short* __restrict__ Yt)
{
  __shared__ float Ws[16][68];
  __shared__ float Xs[16][68];
  const int t  = threadIdx.x;
  const int n0 = blockIdx.x * 64;
  const int b  = blockIdx.z;
  const float* Xb = X + (size_t)b * Cc * Nc;
  const int tx = t & 15, ty = t >> 4;
  const int wo = t >> 2, wk = (t & 3) * 4;
  const int xk = t >> 4, xn = (t & 15) * 4;
  float acc[4][4] = {};
  for (int k0 = 0; k0 < Cc; k0 += 16) {
    float4 w4 = *(const float4*)&W[(size_t)wo * Cc + k0 + wk];
    float4 x4 = *(const float4*)&Xb[(size_t)(k0 + xk) * Nc + n0 + xn];
    Ws[wk + 0][wo] = w4.x; Ws[wk + 1][wo] = w4.y;
    Ws[wk + 2][wo] = w4.z; Ws[wk + 3][wo] = w4.w;
    *(float4*)&Xs[xk][xn] = x4;
    __syncthreads();
#pragma unroll
    for (int kk = 0; kk < 16; ++kk) {
      float4 av = *(const float4*)&Ws[kk][ty * 4];
      float4 bv = *(const float4*)&Xs[kk][tx * 4];
      float aa[4] = {av.x, av.y, av.z, av.w};
      float bb[4] = {bv.x, bv.y, bv.z, bv.w};
#pragma unroll
      for (int i = 0; i < 4; ++i)
#pragma unroll
        for (int j = 0; j < 4; ++j) acc[i][j] += aa[i] * bb[j];
    }
    __syncthreads();
  }
  // Yt[(b*N + n)*64 + o], thread's o = ty*4 + i are consecutive
#pragma unroll
  for (int j = 0; j < 4; ++j) {
    bf16x4 o4;
    o4[0] = f2bf(acc[0][j]); o4[1] = f2bf(acc[1][j]);
    o4[2] = f2bf(acc[2][j]); o4[3] = f2bf(acc[3][j]);
    *(bf16x4*)&Yt[((size_t)b * Nc + n0 + tx * 4 + j) * Dc + ty * 4] = o4;
  }
}

// ---------------------------------------------------------------------------
// conv1x1 -> bf16 natural output [b][c][n] (for v). O = 256.
// ---------------------------------------------------------------------------
__global__ __launch_bounds__(256) void conv_v_bf16_kernel(
    const float* __restrict__ W, const float* __restrict__ X,
    short* __restrict__ Y)
{
  __shared__ float Ws[16][68];
  __shared__ float Xs[16][68];
  const int t  = threadIdx.x;
  const int n0 = blockIdx.x * 64;
  const int o0 = blockIdx.y * 64;
  const int b  = blockIdx.z;
  const float* Xb = X + (size_t)b * Cc * Nc;
  const int tx = t & 15, ty = t >> 4;
  const int wo = t >> 2, wk = (t & 3) * 4;
  const int xk = t >> 4, xn = (t & 15) * 4;
  float acc[4][4] = {};
  for (int k0 = 0; k0 < Cc; k0 += 16) {
    float4 w4 = *(const float4*)&W[(size_t)(o0 + wo) * Cc + k0 + wk];
    float4 x4 = *(const float4*)&Xb[(size_t)(k0 + xk) * Nc + n0 + xn];
    Ws[wk + 0][wo] = w4.x; Ws[wk + 1][wo] = w4.y;
    Ws[wk + 2][wo] = w4.z; Ws[wk + 3][wo] = w4.w;
    *(float4*)&Xs[xk][xn] = x4;
    __syncthreads();
#pragma unroll
    for (int kk = 0; kk < 16; ++kk) {
      float4 av = *(const float4*)&Ws[kk][ty * 4];
      float4 bv = *(const float4*)&Xs[kk][tx * 4];
      float aa[4] = {av.x, av.y, av.z, av.w};
      float bb[4] = {bv.x, bv.y, bv.z, bv.w};
#pragma unroll
      for (int i = 0; i < 4; ++i)
#pragma unroll
        for (int j = 0; j < 4; ++j) acc[i][j] += aa[i] * bb[j];
    }
    __syncthreads();
  }
#pragma unroll
  for (int i = 0; i < 4; ++i) {
    bf16x4 o4;
    o4[0] = f2bf(acc[i][0]); o4[1] = f2bf(acc[i][1]);
    o4[2] = f2bf(acc[i][2]); o4[3] = f2bf(acc[i][3]);
    *(bf16x4*)&Y[((size_t)b * Cc + o0 + ty * 4 + i) * Nc + n0 + tx * 4] = o4;
  }
}

// ---------------------------------------------------------------------------
// MFMA flash attention, KV-split=2, partial unnormalized O (bf16) + (m,l).
// grid (Nc/64, 2, B), block 256 (4 waves).
// QK phase: wave ws owns m-strip [16ws,16ws+16), computes S^T = mfma(K,Q)
//   for a 64-key chunk; softmax is lane-local in m (col = lane&15).
// PV phase: wave ws owns C-strip [64ws,64ws+64); P via XOR-swizzled LDS.
// ---------------------------------------------------------------------------
__global__ __launch_bounds__(256, 2) void attn_mfma_kernel(
    const short* __restrict__ Qt,   // [B][N][64] bf16
    const short* __restrict__ Kt,   // [B][N][64] bf16
    const short* __restrict__ V,    // [B][C][N]  bf16
    short* __restrict__ Op,         // [B][2][C][N] partial O, bf16
    float* __restrict__ Ml)         // [B][2][N][2] (m_run, l_run)
{
  __shared__ __align__(16) short p_lds[64 * 64];  // 64 m-rows x 128B, swizzled
  __shared__ float s_fac[64];

  const int t  = threadIdx.x;
  const int ws = t >> 6;
  const int l  = t & 63;
  const int lr = l & 15;
  const int lg = l >> 4;
  const int m0 = blockIdx.x * 64;
  const int sp = blockIdx.y;
  const int b  = blockIdx.z;

  const short* qp = Qt + ((size_t)b * Nc + m0 + ws * 16 + lr) * Dc + lg * 8;
  const bf16x8 qf0 = *(const bf16x8*)qp;
  const bf16x8 qf1 = *(const bf16x8*)(qp + 32);

  const short* kbase = Kt + ((size_t)b * Nc + sp * 2048 + lr) * Dc + lg * 8;
  const short* vbase = V + ((size_t)b * Cc + ws * 64 + lr) * Nc + sp * 2048 + lg * 8;

  float m_run = -1e30f, l_run = 0.f;
  f32x4 acc[4][4] = {};

  const int  mrow = ws * 16 + lr;
  char*      prow = (char*)p_lds + mrow * 128;
  const int  sw   = (mrow & 7) << 4;

  for (int ch = 0; ch < 32; ++ch) {
    // ---- QK^T
    const short* kp = kbase + ch * 64 * Dc;
    f32x4 st[4] = {};
#pragma unroll
    for (int nt = 0; nt < 4; ++nt) {
      bf16x8 a0 = *(const bf16x8*)(kp + nt * 16 * Dc);
      bf16x8 a1 = *(const bf16x8*)(kp + nt * 16 * Dc + 32);
      st[nt] = __builtin_amdgcn_mfma_f32_16x16x32_bf16(a0, qf0, st[nt], 0, 0, 0);
      st[nt] = __builtin_amdgcn_mfma_f32_16x16x32_bf16(a1, qf1, st[nt], 0, 0, 0);
    }
    // ---- online softmax (own m = lane&15; n spread over regs + lane groups)
    float mx = -1e30f;
#pragma unroll
    for (int nt = 0; nt < 4; ++nt)
#pragma unroll
      for (int r = 0; r < 4; ++r) mx = fmaxf(mx, st[nt][r]);
    mx = fmaxf(mx, __shfl_xor(mx, 16));
    mx = fmaxf(mx, __shfl_xor(mx, 32));
    const float mnew = fmaxf(m_run, mx);
    const float s = __expf(m_run - mnew);
    float p[4][4];
    float sum = 0.f;
#pragma unroll
    for (int nt = 0; nt < 4; ++nt)
#pragma unroll
      for (int r = 0; r < 4; ++r) {
        p[nt][r] = __expf(st[nt][r] - mnew);
        sum += p[nt][r];
      }
    sum += __shfl_xor(sum, 16);
    sum += __shfl_xor(sum, 32);
    l_run = l_run * s + sum;
    m_run = mnew;
#pragma unroll
    for (int nt = 0; nt < 4; ++nt) {
      bf16x4 pb;
      pb[0] = f2bf(p[nt][0]); pb[1] = f2bf(p[nt][1]);
      pb[2] = f2bf(p[nt][2]); pb[3] = f2bf(p[nt][3]);
      *(bf16x4*)(prow + ((nt * 32 + lg * 8) ^ sw)) = pb;
    }
    if (lg == 0) s_fac[ws * 16 + lr] = s;
    __syncthreads();

    // ---- PV
    float scm[4];
#pragma unroll
    for (int mt = 0; mt < 4; ++mt) scm[mt] = s_fac[mt * 16 + lr];
#pragma unroll
    for (int ct = 0; ct < 4; ++ct)
#pragma unroll
      for (int mt = 0; mt < 4; ++mt) {
        acc[ct][mt][0] *= scm[mt]; acc[ct][mt][1] *= scm[mt];
        acc[ct][mt][2] *= scm[mt]; acc[ct][mt][3] *= scm[mt];
      }
    bf16x8 pf[4][2];
#pragma unroll
    for (int mt = 0; mt < 4; ++mt) {
      const int   rm  = mt * 16 + lr;
      const char* pr  = (const char*)p_lds + rm * 128;
      const int   swr = (rm & 7) << 4;
#pragma unroll
      for (int kk = 0; kk < 2; ++kk)
        pf[mt][kk] = *(const bf16x8*)(pr + ((lg * 16 + kk * 64) ^ swr));
    }
    const short* vp = vbase + ch * 64;
#pragma unroll
    for (int ct = 0; ct < 4; ++ct) {
#pragma unroll
      for (int kk = 0; kk < 2; ++kk) {
        bf16x8 va = *(const bf16x8*)(vp + (size_t)ct * 16 * Nc + kk * 32);
#pragma unroll
        for (int mt = 0; mt < 4; ++mt)
          acc[ct][mt] = __builtin_amdgcn_mfma_f32_16x16x32_bf16(va, pf[mt][kk], acc[ct][mt], 0, 0, 0);
      }
    }
    __syncthreads();
  }

  // ---- epilogue: stats + unnormalized partial O
  if (lg == 0) {
    size_t mi = ((size_t)(b * 2 + sp) * Nc + m0 + ws * 16 + lr) * 2;
    Ml[mi]     = m_run;
    Ml[mi + 1] = l_run;
  }
  short* ob = Op + (size_t)(b * 2 + sp) * Cc * Nc;
#pragma unroll
  for (int ct = 0; ct < 4; ++ct)
#pragma unroll
    for (int mt = 0; mt < 4; ++mt)
#pragma unroll
      for (int r = 0; r < 4; ++r) {
        int c = ws * 64 + ct * 16 + lg * 4 + r;
        int m = m0 + mt * 16 + lr;
        ob[(size_t)c * Nc + m] = f2bf(acc[ct][mt][r]);
      }
}

// ---------------------------------------------------------------------------
// Combine the two KV-split partials: R = sum_i e^{m_i-M} O_i / sum_i e^{m_i-M} l_i
// ---------------------------------------------------------------------------
__global__ __launch_bounds__(256) void combine_kernel(
    const short* __restrict__ Op, const float* __restrict__ Ml,
    float* __restrict__ R)
{
  const int idx = blockIdx.x * 256 + threadIdx.x;  // over B*C*(N/4)
  const int m4  = (idx & 1023) * 4;
  const int c   = (idx >> 10) & 255;
  const int b   = idx >> 18;
  const short* o0 = Op + ((size_t)(b * 2 + 0) * Cc + c) * Nc + m4;
  const short* o1 = Op + ((size_t)(b * 2 + 1) * Cc + c) * Nc + m4;
  bf16x4 a = *(const bf16x4*)o0;
  bf16x4 d = *(const bf16x4*)o1;
  const float* ml0 = Ml + (size_t)(b * 2 + 0) * Nc * 2;
  const float* ml1 = Ml + (size_t)(b * 2 + 1) * Nc * 2;
  float4 out;
  float* po = &out.x;
#pragma unroll
  for (int j = 0; j < 4; ++j) {
    int m = m4 + j;
    float m1 = ml0[m * 2], L1 = ml0[m * 2 + 1];
    float m2 = ml1[m * 2], L2 = ml1[m * 2 + 1];
    float M  = fmaxf(m1, m2);
    float w1 = __expf(m1 - M), w2 = __expf(m2 - M);
    po[j] = (w1 * bf2f(a[j]) + w2 * bf2f(d[j])) / (w1 * L1 + w2 * L2);
  }
  *(float4*)&R[((size_t)b * Cc + c) * Nc + m4] = out;
}

// ---------------------------------------------------------------------------
// BN stats + epilogue (unchanged from round 1)
// ---------------------------------------------------------------------------
__global__ __launch_bounds__(256) void bn_stats_kernel(
    const float* __restrict__ T, float* __restrict__ stats)
{
  const int c = blockIdx.x, t = threadIdx.x;
  float s = 0.f, ss = 0.f;
  for (int i = t; i < Bc * Nc; i += 256) {
    int b = i >> 12, n = i & (Nc - 1);
    float v = T[((size_t)b * Cc + c) * Nc + n];
    s += v; ss += v * v;
  }
#pragma unroll
  for (int off = 1; off < 64; off <<= 1) {
    s  += __shfl_xor(s, off);
    ss += __shfl_xor(ss, off);
  }
  __shared__ float rs[4], rss[4];
  int w = t >> 6;
  if ((t & 63) == 0) { rs[w] = s; rss[w] = ss; }
  __syncthreads();
  if (t == 0) {
    s  = rs[0] + rs[1] + rs[2] + rs[3];
    ss = rss[0] + rss[1] + rss[2] + rss[3];
    float inv_n = 1.0f / (float)(Bc * Nc);
    float mean = s * inv_n;
    float var  = ss * inv_n - mean * mean;
    stats[c]      = mean;
    stats[Cc + c] = rsqrtf(var + 1e-5f);
  }
}

__global__ __launch_bounds__(256) void bn_out_kernel(
    const float* __restrict__ T, const float* __restrict__ SRC,
    const float* __restrict__ stats, const float* __restrict__ gamma,
    const float* __restrict__ beta, float* __restrict__ OUT)
{
  const int i = blockIdx.x * 256 + threadIdx.x;
  const int flat = i << 2;
  const int c = (flat >> 12) & (Cc - 1);
  float mean = stats[c], istd = stats[Cc + c];
  float gm = gamma[c], bt = beta[c];
  float4 t4 = *(const float4*)&T[flat];
  float4 s4 = *(const float4*)&SRC[flat];
  float4 o4;
  o4.x = s4.x + fmaxf(0.f, gm * (t4.x - mean) * istd + bt);
  o4.y = s4.y + fmaxf(0.f, gm * (t4.y - mean) * istd + bt);
  o4.z = s4.z + fmaxf(0.f, gm * (t4.z - mean) * istd + bt);
  o4.w = s4.w + fmaxf(0.f, gm * (t4.w - mean) * istd + bt);
  *(float4*)&OUT[flat] = o4;
}

// ---------------------------------------------------------------------------
extern "C" void kernel_launch(void* const* d_in, const int* in_sizes, int n_in,
                              void* d_out, int out_size, void* d_ws, size_t ws_size,
                              hipStream_t stream) {
  const float* x     = (const float*)d_in[0];
  const float* y     = (const float*)d_in[1];
  const float* w_qkx = (const float*)d_in[2];
  const float* w_vx  = (const float*)d_in[3];
  const float* w_tx  = (const float*)d_in[4];
  const float* w_qky = (const float*)d_in[5];
  const float* w_vy  = (const float*)d_in[6];
  const float* w_ty  = (const float*)d_in[7];
  const float* gamma = (const float*)d_in[8];
  const float* beta  = (const float*)d_in[9];

  float* out0 = (float*)d_out;
  float* out1 = out0 + (size_t)Bc * Cc * Nc;

  char* wsb = (char*)d_ws;
  short* qt = (short*)wsb;                               // 2 MB bf16 [B][N][64]
  short* kt = (short*)(wsb + (2u << 20));                // 2 MB
  short* vb = (short*)(wsb + (4u << 20));                // 8 MB bf16 [B][C][N]
  float* rb = (float*)(wsb + (12u << 20));               // 16 MB fp32 [B][C][N]
  float* ml = (float*)(wsb + (28u << 20));               // 256 KB
  float* st = (float*)(wsb + (28u << 20) + (1u << 18));  // BN stats
  char*  shared_reg = wsb + (29u << 20);                 // 16 MB: Op, then t
  short* op = (short*)shared_reg;
  float* tb = (float*)shared_reg;

  for (int br = 0; br < 2; ++br) {
    const float* src = (br == 0) ? x : y;
    const float* tgt = (br == 0) ? y : x;
    const float* wqk = (br == 0) ? w_qkx : w_qky;
    const float* wv  = (br == 0) ? w_vx  : w_vy;
    const float* wt  = (br == 0) ? w_tx  : w_ty;
    float* out       = (br == 0) ? out0 : out1;

    conv_qk_bf16t_kernel<<<dim3(Nc / 64, 1, Bc), 256, 0, stream>>>(wqk, tgt, qt);
    conv_qk_bf16t_kernel<<<dim3(Nc / 64, 1, Bc), 256, 0, stream>>>(wqk, src, kt);
    conv_v_bf16_kernel<<<dim3(Nc / 64, Cc / 64, Bc), 256, 0, stream>>>(wv, src, vb);
    attn_mfma_kernel<<<dim3(Nc / 64, 2, Bc), 256, 0, stream>>>(qt, kt, vb, op, ml);
    combine_kernel<<<(Bc * Cc * (Nc / 4)) / 256, 256, 0, stream>>>(op, ml, rb);
    conv1x1_kernel<<<dim3(Nc / 64, Cc / 64, Bc), 256, 0, stream>>>(wt, rb, tb, Cc);
    bn_stats_kernel<<<Cc, 256, 0, stream>>>(tb, st);
    bn_out_kernel<<<(Bc * Cc * Nc / 4) / 256, 256, 0, stream>>>(tb, src, st, gamma, beta, out);
  }
}